// Round 1
// baseline (289.383 us; speedup 1.0000x reference)
//
#include <hip/hip_runtime.h>

// Shapes (fixed by setup_inputs): B=64 H=16 T=4 Dk=128 Dv=256
#define BH   1024      // B*H
#define TT   4
#define DK   128
#define DV   256

// One block per (b,h). 256 threads; thread i owns state column v=i:
// s[k] = state[k][i], k=0..127, held entirely in VGPRs (unrolled const-index).
// Reductions over k are thread-local dots; k_t/q_t broadcast via LDS.
__global__ __launch_bounds__(256)
void delta_rule_kernel(const float* __restrict__ q,
                       const float* __restrict__ k,
                       const float* __restrict__ v,
                       const float* __restrict__ g,
                       const float* __restrict__ beta,
                       const float* __restrict__ s0,
                       float* __restrict__ out)
{
    const int bh   = blockIdx.x;     // 0..1023
    const int vcol = threadIdx.x;    // 0..255  (owned v column)

    const float* __restrict__ sin_p = s0 + (size_t)bh * DK * DV;
    float* __restrict__ out_p  = out + (size_t)bh * TT * DV;
    float* __restrict__ sout_p = out + (size_t)BH * TT * DV + (size_t)bh * DK * DV;

    const float* __restrict__ kbase = k    + (size_t)bh * TT * DK;
    const float* __restrict__ qbase = q    + (size_t)bh * TT * DK;
    const float* __restrict__ vbase = v    + (size_t)bh * TT * DV;
    const float* __restrict__ gbase = g    + (size_t)bh * TT;
    const float* __restrict__ bbase = beta + (size_t)bh * TT;

    // Load state column: per k, lanes v=0..255 read contiguous floats (coalesced).
    float s[DK];
#pragma unroll
    for (int kk = 0; kk < DK; ++kk)
        s[kk] = sin_p[(size_t)kk * DV + vcol];

    __shared__ float kq[2 * DK];   // [0,DK)=k_t  [DK,2DK)=q_t

    for (int t = 0; t < TT; ++t) {
        __syncthreads();           // previous iter's kq reads done
        if (vcol < DK) kq[vcol]      = kbase[t * DK + vcol];
        else           kq[vcol]      = qbase[t * DK + (vcol - DK)];
        __syncthreads();

        const float gt = expf(gbase[t]);
        const float bt = bbase[t];
        const float vt = vbase[t * DV + vcol];

        // decay + key readout (thread-local dot over k)
        float kv = 0.0f;
#pragma unroll
        for (int kk = 0; kk < DK; ++kk) {
            s[kk] *= gt;
            kv = fmaf(s[kk], kq[kk], kv);
        }

        const float delta = (vt - kv) * bt;

        // rank-1 update + query readout
        float o = 0.0f;
#pragma unroll
        for (int kk = 0; kk < DK; ++kk) {
            s[kk] = fmaf(kq[kk], delta, s[kk]);
            o = fmaf(s[kk], kq[DK + kk], o);
        }

        out_p[t * DV + vcol] = o;
    }

    // Write back final state (coalesced, same pattern as load).
#pragma unroll
    for (int kk = 0; kk < DK; ++kk)
        sout_p[(size_t)kk * DV + vcol] = s[kk];
}

extern "C" void kernel_launch(void* const* d_in, const int* in_sizes, int n_in,
                              void* d_out, int out_size, void* d_ws, size_t ws_size,
                              hipStream_t stream) {
    const float* q    = (const float*)d_in[0];
    const float* k    = (const float*)d_in[1];
    const float* v    = (const float*)d_in[2];
    const float* g    = (const float*)d_in[3];
    const float* beta = (const float*)d_in[4];
    const float* s0   = (const float*)d_in[5];
    float* out = (float*)d_out;

    delta_rule_kernel<<<dim3(BH), dim3(256), 0, stream>>>(q, k, v, g, beta, s0, out);
}

// Round 2
// 262.735 us; speedup vs baseline: 1.1014x; 1.1014x over previous
//
#include <hip/hip_runtime.h>

// Shapes (fixed): B=64 H=16 T=4 Dk=128 Dv=256
#define BH    1024
#define TT    4
#define DK    128
#define DV    256
#define KSEG  8        // k-groups (lanes) cooperating on one v-tile
#define KLEN  16       // k rows per thread = DK/KSEG
#define HALFV 128      // v-columns per block (2 blocks per bh)
#define LDP   17       // padded LDS row stride (16+1, conflict-free)

// Block = 256 threads = 32 v-groups x 8 k-groups. Thread (vg,kg) owns the
// state tile [16*kg .. 16*kg+15] x [4*vg .. 4*vg+3] as float4 s4[16] (64 VGPRs).
// k-dim reductions: in-wave shfl_xor butterfly over the 8 kg lanes (kg = tid&7,
// so partners are adjacent lanes). All state traffic is dwordx4.
__global__ __launch_bounds__(256)
void delta_rule_kernel(const float* __restrict__ q,
                       const float* __restrict__ k,
                       const float* __restrict__ v,
                       const float* __restrict__ g,
                       const float* __restrict__ beta,
                       const float* __restrict__ s0,
                       float* __restrict__ out)
{
    const int bh   = blockIdx.x >> 1;
    const int half = blockIdx.x & 1;
    const int tid  = threadIdx.x;
    const int kg   = tid & (KSEG - 1);            // 0..7 (in-wave, adjacent lanes)
    const int vg   = tid >> 3;                    // 0..31
    const int vcol = half * HALFV + vg * 4;       // first of this thread's 4 v-cols
    const int kr0  = kg * KLEN;                   // first of this thread's 16 k-rows

    const float* __restrict__ sin_p = s0 + (size_t)bh * DK * DV;
    float* __restrict__ out_p  = out + (size_t)bh * TT * DV;
    float* __restrict__ sout_p = out + (size_t)BH * TT * DV + (size_t)bh * DK * DV;

    const float* __restrict__ kbase = k    + (size_t)bh * TT * DK;
    const float* __restrict__ qbase = q    + (size_t)bh * TT * DK;
    const float* __restrict__ vbase = v    + (size_t)bh * TT * DV;
    const float* __restrict__ gbase = g    + (size_t)bh * TT;
    const float* __restrict__ bbase = beta + (size_t)bh * TT;

    // Load state tile: 16 x dwordx4, coalesced (8 vg lanes -> 128B lines).
    float4 s4[KLEN];
#pragma unroll
    for (int kk = 0; kk < KLEN; ++kk)
        s4[kk] = *(const float4*)&sin_p[(size_t)(kr0 + kk) * DV + vcol];

    __shared__ float ks[KSEG * LDP];
    __shared__ float qs[KSEG * LDP];

    for (int t = 0; t < TT; ++t) {
        __syncthreads();   // previous iter's LDS reads done
        if (tid < DK) {
            ks[(tid >> 4) * LDP + (tid & 15)] = kbase[t * DK + tid];
        } else {
            int j = tid - DK;
            qs[(j >> 4) * LDP + (j & 15)] = qbase[t * DK + j];
        }
        __syncthreads();

        const float gt = expf(gbase[t]);
        const float bt = bbase[t];
        const float4 v4 = *(const float4*)&vbase[t * DV + vcol];

        // decay + key readout partial (16-deep, 4 independent chains)
        float4 kv = make_float4(0.f, 0.f, 0.f, 0.f);
#pragma unroll
        for (int kk = 0; kk < KLEN; ++kk) {
            const float kt = ks[kg * LDP + kk];
            s4[kk].x *= gt; s4[kk].y *= gt; s4[kk].z *= gt; s4[kk].w *= gt;
            kv.x = fmaf(s4[kk].x, kt, kv.x);
            kv.y = fmaf(s4[kk].y, kt, kv.y);
            kv.z = fmaf(s4[kk].z, kt, kv.z);
            kv.w = fmaf(s4[kk].w, kt, kv.w);
        }
        // butterfly over the 8 kg lanes -> all lanes hold the full k-sum
#pragma unroll
        for (int m = 1; m < KSEG; m <<= 1) {
            kv.x += __shfl_xor(kv.x, m);
            kv.y += __shfl_xor(kv.y, m);
            kv.z += __shfl_xor(kv.z, m);
            kv.w += __shfl_xor(kv.w, m);
        }

        float4 d4;
        d4.x = (v4.x - kv.x) * bt;
        d4.y = (v4.y - kv.y) * bt;
        d4.z = (v4.z - kv.z) * bt;
        d4.w = (v4.w - kv.w) * bt;

        // rank-1 update + query readout partial
        float4 o4 = make_float4(0.f, 0.f, 0.f, 0.f);
#pragma unroll
        for (int kk = 0; kk < KLEN; ++kk) {
            const float kt = ks[kg * LDP + kk];
            const float qt = qs[kg * LDP + kk];
            s4[kk].x = fmaf(kt, d4.x, s4[kk].x);
            s4[kk].y = fmaf(kt, d4.y, s4[kk].y);
            s4[kk].z = fmaf(kt, d4.z, s4[kk].z);
            s4[kk].w = fmaf(kt, d4.w, s4[kk].w);
            o4.x = fmaf(s4[kk].x, qt, o4.x);
            o4.y = fmaf(s4[kk].y, qt, o4.y);
            o4.z = fmaf(s4[kk].z, qt, o4.z);
            o4.w = fmaf(s4[kk].w, qt, o4.w);
        }
#pragma unroll
        for (int m = 1; m < KSEG; m <<= 1) {
            o4.x += __shfl_xor(o4.x, m);
            o4.y += __shfl_xor(o4.y, m);
            o4.z += __shfl_xor(o4.z, m);
            o4.w += __shfl_xor(o4.w, m);
        }
        if (kg == 0)
            *(float4*)&out_p[t * DV + vcol] = o4;
    }

    // Store final state tile: 16 x dwordx4, coalesced.
#pragma unroll
    for (int kk = 0; kk < KLEN; ++kk)
        *(float4*)&sout_p[(size_t)(kr0 + kk) * DV + vcol] = s4[kk];
}

extern "C" void kernel_launch(void* const* d_in, const int* in_sizes, int n_in,
                              void* d_out, int out_size, void* d_ws, size_t ws_size,
                              hipStream_t stream) {
    const float* q    = (const float*)d_in[0];
    const float* k    = (const float*)d_in[1];
    const float* v    = (const float*)d_in[2];
    const float* g    = (const float*)d_in[3];
    const float* beta = (const float*)d_in[4];
    const float* s0   = (const float*)d_in[5];
    float* out = (float*)d_out;

    delta_rule_kernel<<<dim3(BH * 2), dim3(256), 0, stream>>>(q, k, v, g, beta, s0, out);
}